// Round 3
// baseline (77406.396 us; speedup 1.0000x reference)
//
#include <hip/hip_runtime.h>

#define SEQL 131072
#define HID 48
#define PRED 64

typedef float f32x2 __attribute__((ext_vector_type(2)));

__device__ __forceinline__ float sigm(float v) {
    return 1.0f / (1.0f + __expf(-v));
}
__device__ __forceinline__ float tanh_fast(float v) {
    return 1.0f - 2.0f / (__expf(2.0f * v) + 1.0f);
}

// packed fp32 FMA: acc.lo += a.lo*b.lo, acc.hi += a.hi*b.hi  (VOP3P)
__device__ __forceinline__ void pkfma(f32x2& acc, f32x2 a, f32x2 b) {
    asm("v_pk_fma_f32 %0, %1, %2, %0" : "+v"(acc) : "v"(a), "v"(b));
}

__device__ __forceinline__ float wave_sum(float v) {
#pragma unroll
    for (int off = 32; off > 0; off >>= 1) v += __shfl_xor(v, off, 64);
    return v;
}

#define FOR24(M) M(0) M(1) M(2) M(3) M(4) M(5) M(6) M(7) M(8) M(9) M(10) M(11) \
                 M(12) M(13) M(14) M(15) M(16) M(17) M(18) M(19) M(20) M(21) M(22) M(23)

__global__ __launch_bounds__(64, 1) void lstm_all(
    const float* __restrict__ x,      // 2*SEQL
    const float* __restrict__ W_ih,   // 192*2
    const float* __restrict__ W_hh,   // 192*48
    const float* __restrict__ b_ih,   // 192
    const float* __restrict__ b_hh,   // 192
    const float* __restrict__ W_out,  // 48
    const float* __restrict__ b_out,  // 1
    float* __restrict__ out)          // 64
{
    __shared__ __align__(16) float sh_h[64];  // 48 live + 16 padding slots

    const int k = threadIdx.x;
    const bool live = (k < HID);
    const int r0 = live ? k : 0;      // dead lanes mirror row 0 (harmless, h unused)
    const int r1 = r0 + HID, r2 = r0 + 2 * HID, r3 = r0 + 3 * HID;

    // ---- 96 individually named weight pairs -> guaranteed VGPR residency ----
#define DECLW(i) f32x2 w0_##i, w1_##i, w2_##i, w3_##i;
    FOR24(DECLW)
#undef DECLW
#define LOADW(i)                                         \
    w0_##i = *(const f32x2*)(W_hh + r0 * HID + 2 * (i)); \
    w1_##i = *(const f32x2*)(W_hh + r1 * HID + 2 * (i)); \
    w2_##i = *(const f32x2*)(W_hh + r2 * HID + 2 * (i)); \
    w3_##i = *(const f32x2*)(W_hh + r3 * HID + 2 * (i));
    FOR24(LOADW)
#undef LOADW

    float4 wx01 = make_float4(W_ih[2 * r0], W_ih[2 * r0 + 1],
                              W_ih[2 * r1], W_ih[2 * r1 + 1]);
    float4 wx23 = make_float4(W_ih[2 * r2], W_ih[2 * r2 + 1],
                              W_ih[2 * r3], W_ih[2 * r3 + 1]);
    float4 bs = make_float4(b_ih[r0] + b_hh[r0], b_ih[r1] + b_hh[r1],
                            b_ih[r2] + b_hh[r2], b_ih[r3] + b_hh[r3]);
    if (!live) {  // dead lanes must produce h == 0
        wx01 = make_float4(0.f, 0.f, 0.f, 0.f);
        wx23 = wx01; bs = wx01;
#define ZEROW(i) w0_##i = (f32x2){0.f, 0.f}; w1_##i = w0_##i; w2_##i = w0_##i; w3_##i = w0_##i;
        FOR24(ZEROW)
#undef ZEROW
    }
    const float wo = live ? W_out[r0] : 0.0f;
    const float bo = b_out[0];

    float c = 0.0f;
    float h = 0.0f;
    sh_h[k] = 0.0f;  // single wave: in-order DS, no barrier needed

#define STEP_FMAS(i) {                                   \
        f32x2 hp = *(const f32x2*)(sh_h + 2 * (i));      \
        pkfma(a0, w0_##i, hp);                           \
        pkfma(a1, w1_##i, hp);                           \
        pkfma(a2, w2_##i, hp);                           \
        pkfma(a3, w3_##i, hp);                           \
    }

#define LSTM_STEP(X0, X1) do {                                              \
        f32x2 a0 = {0.f, 0.f}, a1 = {0.f, 0.f};                             \
        f32x2 a2 = {0.f, 0.f}, a3 = {0.f, 0.f};                             \
        FOR24(STEP_FMAS)                                                    \
        float gi = (a0.x + a0.y) + fmaf((X0), wx01.x, fmaf((X1), wx01.y, bs.x)); \
        float gf = (a1.x + a1.y) + fmaf((X0), wx01.z, fmaf((X1), wx01.w, bs.y)); \
        float gg = (a2.x + a2.y) + fmaf((X0), wx23.x, fmaf((X1), wx23.y, bs.z)); \
        float go = (a3.x + a3.y) + fmaf((X0), wx23.z, fmaf((X1), wx23.w, bs.w)); \
        c = fmaf(sigm(gf), c, sigm(gi) * tanh_fast(gg));                    \
        h = sigm(go) * tanh_fast(c);                                        \
        sh_h[k] = h;                                                        \
    } while (0)

    // ---- encoder: 131072 sequential steps, x prefetched 4 deep ----
    const float2* xp = (const float2*)x;
    float2 xq0 = xp[0], xq1 = xp[1], xq2 = xp[2], xq3 = xp[3];
#pragma unroll 4
    for (int t = 0; t < SEQL; ++t) {
        int tn = t + 4;
        if (tn > SEQL - 1) tn = SEQL - 1;
        float2 xn = xp[tn];  // issued now, consumed 4 steps later
        LSTM_STEP(xq0.x, xq0.y);
        xq0 = xq1; xq1 = xq2; xq2 = xq3; xq3 = xn;
    }

    // ---- out0 ----
    float y = wave_sum(wo * h) + bo;
    if (k == 0) out[0] = y;

    // ---- autoregressive decoder ----
    float v0 = xp[SEQL - 1].y;  // last raw input scalar
    float v1 = y;
    for (int d = 1; d < PRED; ++d) {
        LSTM_STEP(v0, v1);
        float yd = wave_sum(wo * h) + bo;
        if (k == 0) out[d] = yd;
        v0 = v1; v1 = yd;
    }
}

extern "C" void kernel_launch(void* const* d_in, const int* in_sizes, int n_in,
                              void* d_out, int out_size, void* d_ws, size_t ws_size,
                              hipStream_t stream) {
    const float* x     = (const float*)d_in[0];
    const float* W_ih  = (const float*)d_in[1];
    const float* W_hh  = (const float*)d_in[2];
    const float* b_ih  = (const float*)d_in[3];
    const float* b_hh  = (const float*)d_in[4];
    const float* W_out = (const float*)d_in[5];
    const float* b_out = (const float*)d_in[6];
    float* out = (float*)d_out;

    hipLaunchKernelGGL(lstm_all, dim3(1), dim3(64), 0, stream,
                       x, W_ih, W_hh, b_ih, b_hh, W_out, b_out, out);
}

// Round 4
// 60967.303 us; speedup vs baseline: 1.2696x; 1.2696x over previous
//
#include <hip/hip_runtime.h>

#define SEQL 131072
#define HID 48
#define PRED 64

typedef float f32x2 __attribute__((ext_vector_type(2)));

__device__ __forceinline__ float sigm(float v) {
    return 1.0f / (1.0f + __expf(-v));
}
__device__ __forceinline__ float tanh_fast(float v) {
    return 1.0f - 2.0f / (__expf(2.0f * v) + 1.0f);
}

// broadcast lane l's value to an SGPR (uniform)
__device__ __forceinline__ float rdlane(float v, int l) {
    return __int_as_float(__builtin_amdgcn_readlane(__float_as_int(v), l));
}

// packed fp32 FMA, h operand forced into an SGPR pair (1 SGPR src is legal)
__device__ __forceinline__ void pkfma_s(f32x2& acc, f32x2 w, f32x2 h) {
    asm("v_pk_fma_f32 %0, %1, %2, %0" : "+v"(acc) : "v"(w), "s"(h));
}

__device__ __forceinline__ float wave_sum(float v) {
#pragma unroll
    for (int off = 32; off > 0; off >>= 1) v += __shfl_xor(v, off, 64);
    return v;
}

#define FOR24(M) M(0) M(1) M(2) M(3) M(4) M(5) M(6) M(7) M(8) M(9) M(10) M(11) \
                 M(12) M(13) M(14) M(15) M(16) M(17) M(18) M(19) M(20) M(21) M(22) M(23)

__global__ __launch_bounds__(64, 1) void lstm_all(
    const float* __restrict__ x,      // 2*SEQL
    const float* __restrict__ W_ih,   // 192*2
    const float* __restrict__ W_hh,   // 192*48
    const float* __restrict__ b_ih,   // 192
    const float* __restrict__ b_hh,   // 192
    const float* __restrict__ W_out,  // 48
    const float* __restrict__ b_out,  // 1
    float* __restrict__ out)          // 64
{
    const int k = threadIdx.x;
    const bool live = (k < HID);
    const int r0 = live ? k : 0;      // dead lanes mirror row 0 (zeroed below)
    const int r1 = r0 + HID, r2 = r0 + 2 * HID, r3 = r0 + 3 * HID;

    // ---- 96 individually named weight pairs -> VGPR resident ----
#define DECLW(i) f32x2 w0_##i, w1_##i, w2_##i, w3_##i;
    FOR24(DECLW)
#undef DECLW
#define LOADW(i)                                         \
    w0_##i = *(const f32x2*)(W_hh + r0 * HID + 2 * (i)); \
    w1_##i = *(const f32x2*)(W_hh + r1 * HID + 2 * (i)); \
    w2_##i = *(const f32x2*)(W_hh + r2 * HID + 2 * (i)); \
    w3_##i = *(const f32x2*)(W_hh + r3 * HID + 2 * (i));
    FOR24(LOADW)
#undef LOADW

    float4 wx01 = make_float4(W_ih[2 * r0], W_ih[2 * r0 + 1],
                              W_ih[2 * r1], W_ih[2 * r1 + 1]);
    float4 wx23 = make_float4(W_ih[2 * r2], W_ih[2 * r2 + 1],
                              W_ih[2 * r3], W_ih[2 * r3 + 1]);
    float4 bs = make_float4(b_ih[r0] + b_hh[r0], b_ih[r1] + b_hh[r1],
                            b_ih[r2] + b_hh[r2], b_ih[r3] + b_hh[r3]);
    if (!live) {  // dead lanes must compute h == 0 always (gates all 0)
        wx01 = make_float4(0.f, 0.f, 0.f, 0.f);
        wx23 = wx01; bs = wx01;
#define ZEROW(i) w0_##i = (f32x2){0.f, 0.f}; w1_##i = w0_##i; w2_##i = w0_##i; w3_##i = w0_##i;
        FOR24(ZEROW)
#undef ZEROW
    }
    const float wo = live ? W_out[r0] : 0.0f;
    const float bo = b_out[0];

    float c = 0.0f;
    float h = 0.0f;

    // h broadcast state: 24 SGPR pairs (uniform)
#define DECLH(i) f32x2 hs##i = {0.f, 0.f};
    FOR24(DECLH)
#undef DECLH

#define STEP_FMAS(i)            \
    pkfma_s(a0, w0_##i, hs##i); \
    pkfma_s(a1, w1_##i, hs##i); \
    pkfma_s(a2, w2_##i, hs##i); \
    pkfma_s(a3, w3_##i, hs##i);

#define GATH(i)                      \
    hs##i.x = rdlane(h, 2 * (i));    \
    hs##i.y = rdlane(h, 2 * (i) + 1);

#define LSTM_STEP(X0, X1) do {                                              \
        f32x2 a0 = {0.f, 0.f}, a1 = {0.f, 0.f};                             \
        f32x2 a2 = {0.f, 0.f}, a3 = {0.f, 0.f};                             \
        FOR24(STEP_FMAS)                                                    \
        float gi = (a0.x + a0.y) + fmaf((X0), wx01.x, fmaf((X1), wx01.y, bs.x)); \
        float gf = (a1.x + a1.y) + fmaf((X0), wx01.z, fmaf((X1), wx01.w, bs.y)); \
        float gg = (a2.x + a2.y) + fmaf((X0), wx23.x, fmaf((X1), wx23.y, bs.z)); \
        float go = (a3.x + a3.y) + fmaf((X0), wx23.z, fmaf((X1), wx23.w, bs.w)); \
        c = fmaf(sigm(gf), c, sigm(gi) * tanh_fast(gg));                    \
        h = sigm(go) * tanh_fast(c);                                        \
        FOR24(GATH)                                                         \
    } while (0)

    // ---- encoder: chunks of 4 steps; next chunk's x (2x float4) issued at
    // chunk top, consumed a full chunk later -> HBM latency fully hidden ----
    const float4* xp4 = (const float4*)x;  // one float4 = 2 steps of x
    float4 cb0 = xp4[0], cb1 = xp4[1];
#pragma unroll 1
    for (int tc = 0; tc < SEQL; tc += 4) {
        const int nb = (tc + 4 < SEQL) ? ((tc + 4) >> 1) : ((SEQL >> 1) - 2);
        float4 nb0 = xp4[nb];
        float4 nb1 = xp4[nb + 1];
        LSTM_STEP(cb0.x, cb0.y);
        LSTM_STEP(cb0.z, cb0.w);
        LSTM_STEP(cb1.x, cb1.y);
        LSTM_STEP(cb1.z, cb1.w);
        cb0 = nb0; cb1 = nb1;
    }

    // ---- out0 ----
    float y = wave_sum(wo * h) + bo;
    if (k == 0) out[0] = y;

    // ---- autoregressive decoder ----
    float v0 = x[2 * SEQL - 1];  // last raw input scalar
    float v1 = y;
#pragma unroll 1
    for (int d = 1; d < PRED; ++d) {
        LSTM_STEP(v0, v1);
        float yd = wave_sum(wo * h) + bo;
        if (k == 0) out[d] = yd;
        v0 = v1; v1 = yd;
    }
}

extern "C" void kernel_launch(void* const* d_in, const int* in_sizes, int n_in,
                              void* d_out, int out_size, void* d_ws, size_t ws_size,
                              hipStream_t stream) {
    const float* x     = (const float*)d_in[0];
    const float* W_ih  = (const float*)d_in[1];
    const float* W_hh  = (const float*)d_in[2];
    const float* b_ih  = (const float*)d_in[3];
    const float* b_hh  = (const float*)d_in[4];
    const float* W_out = (const float*)d_in[5];
    const float* b_out = (const float*)d_in[6];
    float* out = (float*)d_out;

    hipLaunchKernelGGL(lstm_all, dim3(1), dim3(64), 0, stream,
                       x, W_ih, W_hh, b_ih, b_hh, W_out, b_out, out);
}

// Round 5
// 54443.073 us; speedup vs baseline: 1.4218x; 1.1198x over previous
//
#include <hip/hip_runtime.h>

#define SEQL 131072
#define HID 48
#define PRED 64

typedef float f32x2 __attribute__((ext_vector_type(2)));

// packed fp32 FMA (all-VGPR operands)
__device__ __forceinline__ void pkfma(f32x2& acc, f32x2 a, f32x2 b) {
    asm("v_pk_fma_f32 %0, %1, %2, %0" : "+v"(acc) : "v"(a), "v"(b));
}

__device__ __forceinline__ float wave_sum(float v) {
#pragma unroll
    for (int off = 32; off > 0; off >>= 1) v += __shfl_xor(v, off, 64);
    return v;
}

// quad_perm DPP rotate within each group of 4 lanes
#if __has_builtin(__builtin_amdgcn_mov_dpp)
#define QROT(dst, src, CTRL) \
    dst = __int_as_float(__builtin_amdgcn_mov_dpp(__float_as_int(src), CTRL, 0xF, 0xF, true));
#define ROT1 0x39  /* lane gets (g+1)&3 */
#define ROT2 0x4E  /* lane gets (g+2)&3 */
#define ROT3 0x93  /* lane gets (g+3)&3 */
#define SEL_I(val,p1,p2,p3) ((g==0)?(val):(g==1)?(p3):(g==2)?(p2):(p1))
#define SEL_F(val,p1,p2,p3) ((g==0)?(p1):(g==1)?(val):(g==2)?(p3):(p2))
#define SEL_G(val,p1,p2,p3) ((g==0)?(p2):(g==1)?(p1):(g==2)?(val):(p3))
#define SEL_O(val,p1,p2,p3) ((g==0)?(p3):(g==1)?(p2):(g==2)?(p1):(val))
#define EXCH(val,p1,p2,p3) QROT(p1, val, ROT1) QROT(p2, val, ROT2) QROT(p3, val, ROT3)
#else
// fallback: ds_swizzle XOR butterfly (x1 = g^1, x2 = g^2, x3 = g^3)
#define EXCH(val,p1,p2,p3)                                                      \
    p1 = __int_as_float(__builtin_amdgcn_ds_swizzle(__float_as_int(val), 0x041F)); \
    p2 = __int_as_float(__builtin_amdgcn_ds_swizzle(__float_as_int(val), 0x081F)); \
    p3 = __int_as_float(__builtin_amdgcn_ds_swizzle(__float_as_int(p1), 0x081F));
#define SEL_I(val,p1,p2,p3) ((g==0)?(val):(g==1)?(p1):(g==2)?(p2):(p3))
#define SEL_F(val,p1,p2,p3) ((g==0)?(p1):(g==1)?(val):(g==2)?(p3):(p2))
#define SEL_G(val,p1,p2,p3) ((g==0)?(p2):(g==1)?(p3):(g==2)?(val):(p1))
#define SEL_O(val,p1,p2,p3) ((g==0)?(p3):(g==1)?(p2):(g==2)?(p1):(val))
#endif

// i -> accumulator assignment round-robin over 4 accumulators
#define FOR24_2(M) M(0,a0) M(1,a1) M(2,a2) M(3,a3) M(4,a0) M(5,a1) M(6,a2) M(7,a3) \
                   M(8,a0) M(9,a1) M(10,a2) M(11,a3) M(12,a0) M(13,a1) M(14,a2) M(15,a3) \
                   M(16,a0) M(17,a1) M(18,a2) M(19,a3) M(20,a0) M(21,a1) M(22,a2) M(23,a3)

__global__ __launch_bounds__(256, 1) void lstm_all(
    const float* __restrict__ x,      // 2*SEQL
    const float* __restrict__ W_ih,   // 192*2
    const float* __restrict__ W_hh,   // 192*48
    const float* __restrict__ b_ih,   // 192
    const float* __restrict__ b_hh,   // 192
    const float* __restrict__ W_out,  // 48
    const float* __restrict__ b_out,  // 1
    float* __restrict__ out)          // 64
{
    __shared__ __align__(16) float shA[HID];
    __shared__ __align__(16) float shB[HID];
    __shared__ float sh_v[2];

    const int tid  = threadIdx.x;
    const int lane = tid & 63;
    const int wv   = tid >> 6;        // wave id 0..3
    const int g    = lane & 3;        // gate type: 0=i 1=f 2=g 3=o
    const int ul   = lane >> 2;       // local unit 0..15 (12..15 dead)
    const bool live = (ul < 12);
    const int unit = 12 * wv + (live ? ul : 0);
    const int r    = 48 * g + unit;   // W_hh row
    const bool wrh = live && (g == 0);

    // ---- weights: 24 named f32x2 (48 VGPRs) ----
#define DECLW(i, A) f32x2 w##i;
    FOR24_2(DECLW)
#undef DECLW
#define LOADW(i, A) w##i = *(const f32x2*)(W_hh + r * HID + 2 * (i));
    FOR24_2(LOADW)
#undef LOADW
    float wxa = W_ih[2 * r], wxb = W_ih[2 * r + 1];
    float bsum = b_ih[r] + b_hh[r];
    if (!live) {
        wxa = 0.f; wxb = 0.f; bsum = 0.f;
#define ZW(i, A) w##i = (f32x2){0.f, 0.f};
        FOR24_2(ZW)
#undef ZW
    }
    const float scl = (g == 2) ? 2.0f : 1.0f;   // tanh via 2*sigmoid(2v)-1
    const float scB = (g == 2) ? -1.0f : 0.0f;
    const float wo = (lane < HID) ? W_out[lane] : 0.0f;
    const float bo = b_out[0];
    const float x_last = x[2 * SEQL - 1];

    float c = 0.0f;
    if (tid < HID) shA[tid] = 0.0f;
    __syncthreads();

#define FMA1(i, A) { f32x2 hp = *(const f32x2*)((RD) + 2 * (i)); pkfma(A, w##i, hp); }

#define STEP(RDBUF, WRBUF, X0, X1) do {                                       \
        const float* RD = (RDBUF);                                            \
        f32x2 a0 = {0.f,0.f}, a1 = {0.f,0.f}, a2 = {0.f,0.f}, a3 = {0.f,0.f}; \
        FOR24_2(FMA1)                                                         \
        float dot = ((a0.x + a0.y) + (a1.x + a1.y)) +                         \
                    ((a2.x + a2.y) + (a3.x + a3.y));                          \
        float gate = dot + fmaf((X0), wxa, fmaf((X1), wxb, bsum));            \
        float e = __expf(-(gate * scl));                                      \
        float s = 1.0f / (1.0f + e);                                          \
        float val = fmaf(s, scl, scB);  /* sigm or tanh per lane const */     \
        float p1, p2, p3;                                                     \
        EXCH(val, p1, p2, p3)                                                 \
        float iv = SEL_I(val, p1, p2, p3);                                    \
        float fv = SEL_F(val, p1, p2, p3);                                    \
        float gv = SEL_G(val, p1, p2, p3);                                    \
        float ov = SEL_O(val, p1, p2, p3);                                    \
        c = fmaf(fv, c, iv * gv);                                             \
        float e2 = __expf(-2.0f * c);                                         \
        float th = fmaf(2.0f, 1.0f / (1.0f + e2), -1.0f);                     \
        float hn = ov * th;                                                   \
        if (wrh) (WRBUF)[unit] = hn;                                          \
        __syncthreads();                                                      \
    } while (0)

    // ---- encoder: chunks of 8 steps; x via uniform (SGPR) loads, one chunk
    // ahead -> __syncthreads' vmcnt(0) has nothing outstanding ----
    float cx0,cx1,cx2,cx3,cx4,cx5,cx6,cx7,cx8,cx9,cx10,cx11,cx12,cx13,cx14,cx15;
    {
        int b0 = __builtin_amdgcn_readfirstlane(0);
        cx0=x[b0+0]; cx1=x[b0+1]; cx2=x[b0+2]; cx3=x[b0+3];
        cx4=x[b0+4]; cx5=x[b0+5]; cx6=x[b0+6]; cx7=x[b0+7];
        cx8=x[b0+8]; cx9=x[b0+9]; cx10=x[b0+10]; cx11=x[b0+11];
        cx12=x[b0+12]; cx13=x[b0+13]; cx14=x[b0+14]; cx15=x[b0+15];
    }
#pragma unroll 1
    for (int tc = 0; tc < SEQL; tc += 8) {
        int nb = 2 * tc + 16;
        if (nb > 2 * SEQL - 16) nb = 2 * SEQL - 16;
        nb = __builtin_amdgcn_readfirstlane(nb);
        float nx0=x[nb+0], nx1=x[nb+1], nx2=x[nb+2], nx3=x[nb+3];
        float nx4=x[nb+4], nx5=x[nb+5], nx6=x[nb+6], nx7=x[nb+7];
        float nx8=x[nb+8], nx9=x[nb+9], nx10=x[nb+10], nx11=x[nb+11];
        float nx12=x[nb+12], nx13=x[nb+13], nx14=x[nb+14], nx15=x[nb+15];

        STEP(shA, shB, cx0,  cx1);
        STEP(shB, shA, cx2,  cx3);
        STEP(shA, shB, cx4,  cx5);
        STEP(shB, shA, cx6,  cx7);
        STEP(shA, shB, cx8,  cx9);
        STEP(shB, shA, cx10, cx11);
        STEP(shA, shB, cx12, cx13);
        STEP(shB, shA, cx14, cx15);

        cx0=nx0; cx1=nx1; cx2=nx2; cx3=nx3; cx4=nx4; cx5=nx5; cx6=nx6; cx7=nx7;
        cx8=nx8; cx9=nx9; cx10=nx10; cx11=nx11; cx12=nx12; cx13=nx13; cx14=nx14; cx15=nx15;
    }
    // final h lives in shA

    // ---- out0 ----
    if (wv == 0) {
        float contrib = (lane < HID) ? shA[lane] * wo : 0.0f;
        float y = wave_sum(contrib) + bo;
        if (lane == 0) { out[0] = y; sh_v[0] = x_last; sh_v[1] = y; }
    }
    __syncthreads();

    // ---- autoregressive decoder ----
    float* rdp = shA;
    float* wrp = shB;
#pragma unroll 1
    for (int d = 1; d < PRED; ++d) {
        float x0v = sh_v[0];
        float x1v = sh_v[1];
        STEP(rdp, wrp, x0v, x1v);   // ends with __syncthreads
        if (wv == 0) {
            float contrib = (lane < HID) ? wrp[lane] * wo : 0.0f;
            float y = wave_sum(contrib) + bo;
            if (lane == 0) { out[d] = y; sh_v[0] = x1v; sh_v[1] = y; }
        }
        __syncthreads();
        float* tp = rdp; rdp = wrp; wrp = tp;
    }
}

extern "C" void kernel_launch(void* const* d_in, const int* in_sizes, int n_in,
                              void* d_out, int out_size, void* d_ws, size_t ws_size,
                              hipStream_t stream) {
    const float* x     = (const float*)d_in[0];
    const float* W_ih  = (const float*)d_in[1];
    const float* W_hh  = (const float*)d_in[2];
    const float* b_ih  = (const float*)d_in[3];
    const float* b_hh  = (const float*)d_in[4];
    const float* W_out = (const float*)d_in[5];
    const float* b_out = (const float*)d_in[6];
    float* out = (float*)d_out;

    hipLaunchKernelGGL(lstm_all, dim3(1), dim3(256), 0, stream,
                       x, W_ih, W_hh, b_ih, b_hh, W_out, b_out, out);
}